// Round 3
// baseline (730.182 us; speedup 1.0000x reference)
//
#include <hip/hip_runtime.h>

typedef __bf16 bf16;
typedef __bf16 bf16x8 __attribute__((ext_vector_type(8)));
typedef float f32x4 __attribute__((ext_vector_type(4)));

#define N_ROWS 65536

// padded weight shapes (row-major [out][k]), bf16, in d_ws
#define W1P_E  (208 * 768)
#define W12P_E (112 * 224)
#define W13P_E (112 * 128)
#define W2P_E  (512 * 128)
#define WP_TOTAL (W1P_E + W12P_E + W13P_E + W2P_E)   // 264704 elems
#define BP_OFF_BYTES (WP_TOTAL * 2)                  // 529408
#define BP_FLOATS 944                                // b1p[208] b12p[112] b13p[112] b2p[512]
#define ACC_OFF_BYTES (BP_OFF_BYTES + BP_FLOATS * 4) // 533184 (16B aligned)
#define ACC_FLOATS 259                               // [0..255] colsum, [256] p0, [257] S, [258] p3

// LDS strides (bf16 elems; row stride bytes 16B-divisible)
#define X1_STRIDE 232
#define X23_STRIDE 136

__global__ void pack_kernel(const float* __restrict__ W1, const float* __restrict__ b1,
                            const float* __restrict__ W12, const float* __restrict__ b12,
                            const float* __restrict__ W13, const float* __restrict__ b13,
                            const float* __restrict__ W2, const float* __restrict__ b2,
                            bf16* __restrict__ wp, float* __restrict__ bp) {
  int i = blockIdx.x * 256 + threadIdx.x;
  if (i < WP_TOTAL) {
    float v = 0.0f;
    if (i < W1P_E) {
      int o = i / 768, k = i - o * 768;
      if (o < 200) v = W1[o * 768 + k];
    } else if (i < W1P_E + W12P_E) {
      int j = i - W1P_E;
      int o = j / 224, k = j - o * 224;
      if (o < 100 && k < 200) v = W12[o * 200 + k];
    } else if (i < W1P_E + W12P_E + W13P_E) {
      int j = i - (W1P_E + W12P_E);
      int o = j / 128, k = j - o * 128;
      if (o < 100 && k < 100) v = W13[o * 100 + k];
    } else {
      int j = i - (W1P_E + W12P_E + W13P_E);
      int o = j / 128, k = j - o * 128;
      if (k < 100) v = W2[o * 100 + k];
    }
    wp[i] = (bf16)v;
  } else {
    int j = i - WP_TOTAL;
    if (j < BP_FLOATS) {
      float v = 0.0f;
      if (j < 208)      { if (j < 200) v = b1[j]; }
      else if (j < 320) { int o = j - 208; if (o < 100) v = b12[o]; }
      else if (j < 432) { int o = j - 320; if (o < 100) v = b13[o]; }
      else              { v = b2[j - 432]; }
      bp[j] = v;
    }
  }
}

__device__ inline bf16x8 cvt8(const float* __restrict__ p) {
  f32x4 lo = *(const f32x4*)p;
  f32x4 hi = *(const f32x4*)(p + 4);
  bf16x8 r;
#pragma unroll
  for (int i = 0; i < 4; i++) { r[i] = (bf16)lo[i]; r[4 + i] = (bf16)hi[i]; }
  return r;
}

#define MFMA(a, b, c) __builtin_amdgcn_mfma_f32_16x16x32_bf16((a), (b), (c), 0, 0, 0)

// Block = 128 threads = 2 waves; each wave computes 32 rows (2 M-tiles of 16).
// Every weight B-fragment load feeds 2 MFMAs. Activations live in per-wave
// private LDS slices -> NO __syncthreads anywhere (in-order per-wave LDS).
// x3 overlays x1's LDS region (x1 dead after layer-2 k-loop).
// MFMA 16x16x32 bf16. A: lane holds A[m=lane&15][k=quad*8+j]. B: lane holds
// B[k][n=lane&15] = W[n][k] (contiguous from W row). C/D: reg r holds
// D[row=quad*4+r][col=lane&15].
__global__ __launch_bounds__(128, 2) void mlp_main(
    const float* __restrict__ input, const float* __restrict__ h,
    const bf16* __restrict__ wp, const float* __restrict__ bp,
    float* __restrict__ out, float* __restrict__ p0_accum) {
  __shared__ __align__(16) bf16 x1s[2][32][X1_STRIDE];   // 29696 B (reused as x3)
  __shared__ __align__(16) bf16 x2s[2][32][X23_STRIDE];  // 17408 B

  const int lane = threadIdx.x & 63;
  const int wave = threadIdx.x >> 6;
  const int c16 = lane & 15;
  const int quad = lane >> 4;
  const int m0 = blockIdx.x * 64 + wave * 32;

  const bf16* W1p  = wp;
  const bf16* W12p = wp + W1P_E;
  const bf16* W13p = wp + W1P_E + W12P_E;
  const bf16* W2p  = wp + W1P_E + W12P_E + W13P_E;
  const float* b1p  = bp;
  const float* b12p = bp + 208;
  const float* b13p = bp + 320;
  const float* b2p  = bp + 432;

  bf16* x3b = &x1s[wave][0][0];  // x3: [32][X23_STRIDE] inside x1's region

  // ---------------- Layer 1: (32x768) @ W1p^T -> 32x208 ----------------
  f32x4 acc1[2][13];
#pragma unroll
  for (int mt = 0; mt < 2; mt++)
#pragma unroll
    for (int t = 0; t < 13; t++) acc1[mt][t] = (f32x4){0.f, 0.f, 0.f, 0.f};

  const float* arow0 = input + (size_t)(m0 + c16) * 512;
  const float* arow1 = input + (size_t)(m0 + 16 + c16) * 512;
  const float* hrow0 = h + (size_t)(m0 + c16) * 256;
  const float* hrow1 = h + (size_t)(m0 + 16 + c16) * 256;
#pragma unroll
  for (int ks = 0; ks < 24; ks++) {
    const int k0 = ks * 32;
    bf16x8 a0, a1;
    if (k0 < 512) {
      a0 = cvt8(arow0 + k0 + quad * 8);
      a1 = cvt8(arow1 + k0 + quad * 8);
    } else {
      a0 = cvt8(hrow0 + (k0 - 512) + quad * 8);
      a1 = cvt8(hrow1 + (k0 - 512) + quad * 8);
    }
    const bf16* bb = W1p + (size_t)c16 * 768 + k0 + quad * 8;
#pragma unroll
    for (int t = 0; t < 13; t++) {
      bf16x8 b = *(const bf16x8*)(bb + t * 16 * 768);
      acc1[0][t] = MFMA(a0, b, acc1[0][t]);
      acc1[1][t] = MFMA(a1, b, acc1[1][t]);
    }
  }
#pragma unroll
  for (int mt = 0; mt < 2; mt++)
#pragma unroll
    for (int t = 0; t < 13; t++) {
      const int o = t * 16 + c16;
      const float bias = b1p[o];
#pragma unroll
      for (int r = 0; r < 4; r++) {
        float v = fmaxf(acc1[mt][t][r] + bias, 0.0f);
        x1s[wave][mt * 16 + quad * 4 + r][o] = (bf16)v;
      }
    }
  for (int idx = lane; idx < 512; idx += 64)
    x1s[wave][idx >> 4][208 + (idx & 15)] = (bf16)0.0f;

  // ---------------- Layer 2: (32x224) @ W12p^T -> 32x112 ----------------
  f32x4 acc2[2][7];
#pragma unroll
  for (int mt = 0; mt < 2; mt++)
#pragma unroll
    for (int t = 0; t < 7; t++) acc2[mt][t] = (f32x4){0.f, 0.f, 0.f, 0.f};
#pragma unroll
  for (int ks = 0; ks < 7; ks++) {
    const int k0 = ks * 32;
    bf16x8 a0 = *(const bf16x8*)&x1s[wave][c16][k0 + quad * 8];
    bf16x8 a1 = *(const bf16x8*)&x1s[wave][16 + c16][k0 + quad * 8];
    const bf16* bb = W12p + (size_t)c16 * 224 + k0 + quad * 8;
#pragma unroll
    for (int t = 0; t < 7; t++) {
      bf16x8 b = *(const bf16x8*)(bb + t * 16 * 224);
      acc2[0][t] = MFMA(a0, b, acc2[0][t]);
      acc2[1][t] = MFMA(a1, b, acc2[1][t]);
    }
  }
#pragma unroll
  for (int mt = 0; mt < 2; mt++)
#pragma unroll
    for (int t = 0; t < 7; t++) {
      const int o = t * 16 + c16;
      const float bias = b12p[o];
#pragma unroll
      for (int r = 0; r < 4; r++) {
        float v = fmaxf(acc2[mt][t][r] + bias, 0.0f);
        x2s[wave][mt * 16 + quad * 4 + r][o] = (bf16)v;
      }
    }
  for (int idx = lane; idx < 512; idx += 64)
    x2s[wave][idx >> 4][112 + (idx & 15)] = (bf16)0.0f;

  // ---------------- Layer 3: (32x128) @ W13p^T -> 32x112 (into x1's LDS) ----------------
  f32x4 acc3[2][7];
#pragma unroll
  for (int mt = 0; mt < 2; mt++)
#pragma unroll
    for (int t = 0; t < 7; t++) acc3[mt][t] = (f32x4){0.f, 0.f, 0.f, 0.f};
#pragma unroll
  for (int ks = 0; ks < 4; ks++) {
    const int k0 = ks * 32;
    bf16x8 a0 = *(const bf16x8*)&x2s[wave][c16][k0 + quad * 8];
    bf16x8 a1 = *(const bf16x8*)&x2s[wave][16 + c16][k0 + quad * 8];
    const bf16* bb = W13p + (size_t)c16 * 128 + k0 + quad * 8;
#pragma unroll
    for (int t = 0; t < 7; t++) {
      bf16x8 b = *(const bf16x8*)(bb + t * 16 * 128);
      acc3[0][t] = MFMA(a0, b, acc3[0][t]);
      acc3[1][t] = MFMA(a1, b, acc3[1][t]);
    }
  }
#pragma unroll
  for (int mt = 0; mt < 2; mt++)
#pragma unroll
    for (int t = 0; t < 7; t++) {
      const int o = t * 16 + c16;
      const float bias = b13p[o];
#pragma unroll
      for (int r = 0; r < 4; r++) {
        float v = fmaxf(acc3[mt][t][r] + bias, 0.0f);
        x3b[(mt * 16 + quad * 4 + r) * X23_STRIDE + o] = (bf16)v;
      }
    }
  for (int idx = lane; idx < 512; idx += 64)
    x3b[(idx >> 4) * X23_STRIDE + 112 + (idx & 15)] = (bf16)0.0f;

  // ---------------- Layer 4: (32x128) @ W2p^T -> 32x512 (+ part0), 2 col-groups ----------------
  float p0local = 0.0f;
#pragma unroll
  for (int g = 0; g < 2; g++) {
    f32x4 acc4[2][16];
#pragma unroll
    for (int mt = 0; mt < 2; mt++)
#pragma unroll
      for (int t = 0; t < 16; t++) acc4[mt][t] = (f32x4){0.f, 0.f, 0.f, 0.f};
#pragma unroll
    for (int ks = 0; ks < 4; ks++) {
      const int k0 = ks * 32;
      bf16x8 a0 = *(const bf16x8*)&x3b[c16 * X23_STRIDE + k0 + quad * 8];
      bf16x8 a1 = *(const bf16x8*)&x3b[(16 + c16) * X23_STRIDE + k0 + quad * 8];
      const bf16* bb = W2p + (size_t)(g * 256 + c16) * 128 + k0 + quad * 8;
#pragma unroll
      for (int t = 0; t < 16; t++) {
        bf16x8 b = *(const bf16x8*)(bb + t * 16 * 128);
        acc4[0][t] = MFMA(a0, b, acc4[0][t]);
        acc4[1][t] = MFMA(a1, b, acc4[1][t]);
      }
    }
#pragma unroll
    for (int mt = 0; mt < 2; mt++)
#pragma unroll
      for (int t = 0; t < 16; t++) {
        const int o = g * 256 + t * 16 + c16;
        const float bias = b2p[o];
#pragma unroll
        for (int r = 0; r < 4; r++) {
          const int grow = m0 + mt * 16 + quad * 4 + r;
          float v = acc4[mt][t][r] + bias;
          out[(size_t)grow * 512 + o] = v;
          if (grow < N_ROWS - 1) {
            float d = v - input[(size_t)(grow + 1) * 512 + o];
            p0local += d * d;
          }
        }
      }
  }
#pragma unroll
  for (int off = 32; off > 0; off >>= 1) p0local += __shfl_down(p0local, off);
  if (lane == 0) atomicAdd(p0_accum, p0local);
}

// mu / S / part3 over h. 512 blocks x 128 rows; thread (c=t&63, rg=t>>6)
// covers cols 4c..4c+3, rows start..start+31 (float4 loads, 4-way row ||ism).
__global__ __launch_bounds__(256) void reduce_h(const float* __restrict__ h, float* __restrict__ acc) {
  __shared__ f32x4 cbuf[256];
  __shared__ float redS[256];
  __shared__ float redP[256];
  const int t = threadIdx.x;
  const int c = t & 63;
  const int rg = t >> 6;
  const int start = blockIdx.x * 128 + rg * 32;

  const float* base = h + (size_t)start * 256 + c * 4;
  f32x4 prev = *(const f32x4*)base;
  f32x4 csum = prev;
  f32x4 s2v = prev * prev;
  f32x4 p3v = (f32x4){0.f, 0.f, 0.f, 0.f};
#pragma unroll 8
  for (int r = 1; r < 32; r++) {
    f32x4 v = *(const f32x4*)(base + (size_t)r * 256);
    csum += v;
    s2v += v * v;
    f32x4 d = v - prev;
#pragma unroll
    for (int i = 0; i < 4; i++) p3v[i] += __builtin_fabsf(d[i]);
    prev = v;
  }
  if (start + 32 < N_ROWS) {
    f32x4 v = *(const f32x4*)(base + (size_t)32 * 256);
    f32x4 d = v - prev;
#pragma unroll
    for (int i = 0; i < 4; i++) p3v[i] += __builtin_fabsf(d[i]);
  }
  cbuf[t] = csum;
  redS[t] = s2v[0] + s2v[1] + s2v[2] + s2v[3];
  redP[t] = p3v[0] + p3v[1] + p3v[2] + p3v[3];
  __syncthreads();
  if (rg == 0) {
    f32x4 s = cbuf[c] + cbuf[c + 64] + cbuf[c + 128] + cbuf[c + 192];
    atomicAdd(&acc[4 * c + 0], s[0]);
    atomicAdd(&acc[4 * c + 1], s[1]);
    atomicAdd(&acc[4 * c + 2], s[2]);
    atomicAdd(&acc[4 * c + 3], s[3]);
  }
  for (int s = 128; s > 0; s >>= 1) {
    if (t < s) { redS[t] += redS[t + s]; redP[t] += redP[t + s]; }
    __syncthreads();
  }
  if (t == 0) {
    atomicAdd(&acc[257], redS[0]);
    atomicAdd(&acc[258], redP[0]);
  }
}

__global__ void finalize(const float* __restrict__ acc, float* __restrict__ out) {
  __shared__ float red[256];
  const int t = threadIdx.x;
  red[t] = fabsf(acc[t]);  // |colsum|
  __syncthreads();
  for (int s = 128; s > 0; s >>= 1) {
    if (t < s) red[t] += red[t + s];
    __syncthreads();
  }
  if (t == 0) {
    float part1 = red[0] / 65536.0f / 256.0f;
    float part0 = sqrtf(acc[256]) / 65535.0f;
    float part2 = fabsf(acc[257] / (65536.0f * 256.0f) - 1.0f);
    float part3 = acc[258] / (65535.0f * 256.0f);
    out[(size_t)N_ROWS * 512 + 0] = part0;
    out[(size_t)N_ROWS * 512 + 1] = part1;
    out[(size_t)N_ROWS * 512 + 2] = part2;
    out[(size_t)N_ROWS * 512 + 3] = part3;
  }
}

extern "C" void kernel_launch(void* const* d_in, const int* in_sizes, int n_in,
                              void* d_out, int out_size, void* d_ws, size_t ws_size,
                              hipStream_t stream) {
  const float* input = (const float*)d_in[0];
  const float* h   = (const float*)d_in[1];
  const float* W1  = (const float*)d_in[2];
  const float* b1  = (const float*)d_in[3];
  const float* W12 = (const float*)d_in[4];
  const float* b12 = (const float*)d_in[5];
  const float* W13 = (const float*)d_in[6];
  const float* b13 = (const float*)d_in[7];
  const float* W2  = (const float*)d_in[8];
  const float* b2  = (const float*)d_in[9];
  float* out = (float*)d_out;

  bf16* wp = (bf16*)d_ws;
  float* bp = (float*)((char*)d_ws + BP_OFF_BYTES);
  float* acc = (float*)((char*)d_ws + ACC_OFF_BYTES);

  hipMemsetAsync(acc, 0, ACC_FLOATS * sizeof(float), stream);
  pack_kernel<<<(WP_TOTAL + BP_FLOATS + 255) / 256, 256, 0, stream>>>(
      W1, b1, W12, b12, W13, b13, W2, b2, wp, bp);
  mlp_main<<<N_ROWS / 64, 128, 0, stream>>>(input, h, wp, bp, out, acc + 256);
  reduce_h<<<N_ROWS / 128, 256, 0, stream>>>(h, acc);
  finalize<<<1, 256, 0, stream>>>(acc, out);
}

// Round 4
// 490.196 us; speedup vs baseline: 1.4896x; 1.4896x over previous
//
#include <hip/hip_runtime.h>

typedef __bf16 bf16;
typedef __bf16 bf16x8 __attribute__((ext_vector_type(8)));
typedef float f32x4 __attribute__((ext_vector_type(4)));

#define N_ROWS 65536

// padded weight shapes (row-major [out][k]), bf16, in d_ws
#define W1P_E  (208 * 768)
#define W12P_E (112 * 224)
#define W13P_E (112 * 128)
#define W2P_E  (512 * 128)
#define WP_TOTAL (W1P_E + W12P_E + W13P_E + W2P_E)   // 264704 elems
#define BP_OFF_BYTES (WP_TOTAL * 2)                  // 529408
#define BP_FLOATS 944                                // b1p[208] b12p[112] b13p[112] b2p[512]
#define ACC_OFF_BYTES (BP_OFF_BYTES + BP_FLOATS * 4) // 533184 (16B aligned)
#define ACC_FLOATS 259                               // [0..255] colsum, [256] p0, [257] S, [258] p3

__global__ void pack_kernel(const float* __restrict__ W1, const float* __restrict__ b1,
                            const float* __restrict__ W12, const float* __restrict__ b12,
                            const float* __restrict__ W13, const float* __restrict__ b13,
                            const float* __restrict__ W2, const float* __restrict__ b2,
                            bf16* __restrict__ wp, float* __restrict__ bp) {
  int i = blockIdx.x * 256 + threadIdx.x;
  if (i < WP_TOTAL) {
    float v = 0.0f;
    if (i < W1P_E) {
      int o = i / 768, k = i - o * 768;
      if (o < 200) v = W1[o * 768 + k];
    } else if (i < W1P_E + W12P_E) {
      int j = i - W1P_E;
      int o = j / 224, k = j - o * 224;
      if (o < 100 && k < 200) v = W12[o * 200 + k];
    } else if (i < W1P_E + W12P_E + W13P_E) {
      int j = i - (W1P_E + W12P_E);
      int o = j / 128, k = j - o * 128;
      if (o < 100 && k < 100) v = W13[o * 100 + k];
    } else {
      int j = i - (W1P_E + W12P_E + W13P_E);
      int o = j / 128, k = j - o * 128;
      if (k < 100) v = W2[o * 100 + k];
    }
    wp[i] = (bf16)v;
  } else {
    int j = i - WP_TOTAL;
    if (j < BP_FLOATS) {
      float v = 0.0f;
      if (j < 208)      { if (j < 200) v = b1[j]; }
      else if (j < 320) { int o = j - 208; if (o < 100) v = b12[o]; }
      else if (j < 432) { int o = j - 320; if (o < 100) v = b13[o]; }
      else              { v = b2[j - 432]; }
      bp[j] = v;
    }
  }
}

__device__ inline bf16x8 cvt8(const float* __restrict__ p) {
  f32x4 lo = *(const f32x4*)p;
  f32x4 hi = *(const f32x4*)(p + 4);
  bf16x8 r;
#pragma unroll
  for (int i = 0; i < 4; i++) { r[i] = (bf16)lo[i]; r[4 + i] = (bf16)hi[i]; }
  return r;
}

#define MFMA(a, b, c) __builtin_amdgcn_mfma_f32_16x16x32_bf16((a), (b), (c), 0, 0, 0)

// ---- cooperative weight k-slice staging (block of 256 threads) ----
// Slice = R rows x 32 k-elems (64B/row), stored row-major with seg-XOR swizzle:
// phys_seg = seg ^ ((row ^ (row>>2)) & 3)  -> conflict-free ds_write_b128 and
// ds_read_b128 (every 8 consecutive lanes hit 8 distinct bank-quads).
template<int ITERS, int R, int SRC_STRIDE>
__device__ inline void stage_load(bf16x8* r, const bf16* __restrict__ src, int k0, int tid) {
#pragma unroll
  for (int i = 0; i < ITERS; i++) {
    int e = tid + i * 256;
    if (ITERS * 256 == R * 4 || e < R * 4) {
      int row = e >> 2, seg = e & 3;
      r[i] = *(const bf16x8*)(src + (size_t)row * SRC_STRIDE + k0 + seg * 8);
    }
  }
}
template<int ITERS, int R>
__device__ inline void stage_write(bf16* dst, const bf16x8* r, int tid) {
#pragma unroll
  for (int i = 0; i < ITERS; i++) {
    int e = tid + i * 256;
    if (ITERS * 256 == R * 4 || e < R * 4) {
      int row = e >> 2, seg = e & 3;
      int ps = seg ^ ((row ^ (row >> 2)) & 3);
      *(bf16x8*)(dst + row * 32 + ps * 8) = r[i];
    }
  }
}

// Block = 256 threads = 4 waves; each wave runs 16 rows through all 4 layers.
// Weights staged block-cooperatively into double-buffered LDS k-slices; one
// __syncthreads per k-step. Activations per-wave private in one overlaid LDS
// region (x1 dies before x2 is written; x2 dies before x3 is written).
// MFMA 16x16x32 bf16. A: lane holds A[m=lane&15][k=quad*8+j]. B: lane holds
// B[k][n=c16] = W[n][k]. C/D: reg r holds D[row=quad*4+r][col=c16].
__global__ __launch_bounds__(256, 4) void mlp_main(
    const float* __restrict__ input, const float* __restrict__ h,
    const bf16* __restrict__ wp, const float* __restrict__ bp,
    float* __restrict__ out, float* __restrict__ p0_accum) {
  __shared__ __align__(16) bf16 acts[4][3712];   // 7424 B/wave: x1 16x232 | x2/x3 16x136 overlay
  __shared__ __align__(16) bf16 wbuf[2][6656];   // 2 x 13312 B slices

  const int tid = threadIdx.x;
  const int lane = tid & 63;
  const int wave = tid >> 6;
  const int c16 = lane & 15;
  const int quad = lane >> 4;
  const int m0 = blockIdx.x * 64 + wave * 16;
  const int qs8 = (quad ^ ((c16 ^ (c16 >> 2)) & 3)) * 8;  // swizzled seg offset (elems)

  const bf16* W1p  = wp;
  const bf16* W12p = wp + W1P_E;
  const bf16* W13p = wp + W1P_E + W12P_E;
  const bf16* W2p  = wp + W1P_E + W12P_E + W13P_E;
  const float* b1p  = bp;
  const float* b12p = bp + 208;
  const float* b13p = bp + 320;
  const float* b2p  = bp + 432;

  bf16* actw = &acts[wave][0];
  bf16x8 sreg[4];

  // ---------------- Layer 1: (16x768) @ W1p^T -> 16x208 ----------------
  f32x4 acc1[13];
#pragma unroll
  for (int t = 0; t < 13; t++) acc1[t] = (f32x4){0.f, 0.f, 0.f, 0.f};

  stage_load<4, 208, 768>(sreg, W1p, 0, tid);
  stage_write<4, 208>(wbuf[0], sreg, tid);
  __syncthreads();

  const float* arow = input + (size_t)(m0 + c16) * 512;
  const float* hrow = h + (size_t)(m0 + c16) * 256;
  for (int ks = 0; ks < 24; ks++) {
    if (ks + 1 < 24) stage_load<4, 208, 768>(sreg, W1p, (ks + 1) * 32, tid);
    const int k0 = ks * 32;
    bf16x8 a = (k0 < 512) ? cvt8(arow + k0 + quad * 8) : cvt8(hrow + (k0 - 512) + quad * 8);
    const bf16* buf = wbuf[ks & 1];
#pragma unroll
    for (int t = 0; t < 13; t++) {
      bf16x8 b = *(const bf16x8*)(buf + (t * 16 + c16) * 32 + qs8);
      acc1[t] = MFMA(a, b, acc1[t]);
    }
    if (ks + 1 < 24) stage_write<4, 208>(wbuf[(ks + 1) & 1], sreg, tid);
    __syncthreads();
  }
#pragma unroll
  for (int t = 0; t < 13; t++) {
    const float bias = b1p[t * 16 + c16];
#pragma unroll
    for (int r = 0; r < 4; r++)
      actw[(quad * 4 + r) * 232 + t * 16 + c16] = (bf16)fmaxf(acc1[t][r] + bias, 0.0f);
  }
  for (int idx = lane; idx < 256; idx += 64)
    actw[(idx >> 4) * 232 + 208 + (idx & 15)] = (bf16)0.0f;

  // ---------------- Layer 2: (16x224) @ W12p^T -> 16x112 ----------------
  f32x4 acc2[7];
#pragma unroll
  for (int t = 0; t < 7; t++) acc2[t] = (f32x4){0.f, 0.f, 0.f, 0.f};

  stage_load<2, 112, 224>(sreg, W12p, 0, tid);
  stage_write<2, 112>(wbuf[0], sreg, tid);
  __syncthreads();
  for (int ks = 0; ks < 7; ks++) {
    if (ks + 1 < 7) stage_load<2, 112, 224>(sreg, W12p, (ks + 1) * 32, tid);
    const int k0 = ks * 32;
    bf16x8 a = *(const bf16x8*)(actw + c16 * 232 + k0 + quad * 8);
    const bf16* buf = wbuf[ks & 1];
#pragma unroll
    for (int t = 0; t < 7; t++) {
      bf16x8 b = *(const bf16x8*)(buf + (t * 16 + c16) * 32 + qs8);
      acc2[t] = MFMA(a, b, acc2[t]);
    }
    if (ks + 1 < 7) stage_write<2, 112>(wbuf[(ks + 1) & 1], sreg, tid);
    __syncthreads();
  }
  // x2 overlays x1's bytes (x1 dead after the k-loop above)
#pragma unroll
  for (int t = 0; t < 7; t++) {
    const float bias = b12p[t * 16 + c16];
#pragma unroll
    for (int r = 0; r < 4; r++)
      actw[(quad * 4 + r) * 136 + t * 16 + c16] = (bf16)fmaxf(acc2[t][r] + bias, 0.0f);
  }
  for (int idx = lane; idx < 256; idx += 64)
    actw[(idx >> 4) * 136 + 112 + (idx & 15)] = (bf16)0.0f;

  // ---------------- Layer 3: (16x128) @ W13p^T -> 16x112 ----------------
  f32x4 acc3[7];
#pragma unroll
  for (int t = 0; t < 7; t++) acc3[t] = (f32x4){0.f, 0.f, 0.f, 0.f};

  stage_load<2, 112, 128>(sreg, W13p, 0, tid);
  stage_write<2, 112>(wbuf[0], sreg, tid);
  __syncthreads();
  for (int ks = 0; ks < 4; ks++) {
    if (ks + 1 < 4) stage_load<2, 112, 128>(sreg, W13p, (ks + 1) * 32, tid);
    const int k0 = ks * 32;
    bf16x8 a = *(const bf16x8*)(actw + c16 * 136 + k0 + quad * 8);
    const bf16* buf = wbuf[ks & 1];
#pragma unroll
    for (int t = 0; t < 7; t++) {
      bf16x8 b = *(const bf16x8*)(buf + (t * 16 + c16) * 32 + qs8);
      acc3[t] = MFMA(a, b, acc3[t]);
    }
    if (ks + 1 < 4) stage_write<2, 112>(wbuf[(ks + 1) & 1], sreg, tid);
    __syncthreads();
  }
  // x3 overwrites x2 in place (x2 dead after the k-loop above; same wave, in-order LDS)
#pragma unroll
  for (int t = 0; t < 7; t++) {
    const float bias = b13p[t * 16 + c16];
#pragma unroll
    for (int r = 0; r < 4; r++)
      actw[(quad * 4 + r) * 136 + t * 16 + c16] = (bf16)fmaxf(acc3[t][r] + bias, 0.0f);
  }
  for (int idx = lane; idx < 256; idx += 64)
    actw[(idx >> 4) * 136 + 112 + (idx & 15)] = (bf16)0.0f;

  // ---------------- Layer 4: (16x128) @ W2p^T -> 16x512 (+ part0), 4 col-groups ----------------
  float p0local = 0.0f;
  for (int g = 0; g < 4; g++) {
    f32x4 acc4[8];
#pragma unroll
    for (int t = 0; t < 8; t++) acc4[t] = (f32x4){0.f, 0.f, 0.f, 0.f};

    const bf16* Wg = W2p + (size_t)g * 128 * 128;
    stage_load<2, 128, 128>(sreg, Wg, 0, tid);
    stage_write<2, 128>(wbuf[0], sreg, tid);
    __syncthreads();
    for (int ks = 0; ks < 4; ks++) {
      if (ks + 1 < 4) stage_load<2, 128, 128>(sreg, Wg, (ks + 1) * 32, tid);
      const int k0 = ks * 32;
      bf16x8 a = *(const bf16x8*)(actw + c16 * 136 + k0 + quad * 8);
      const bf16* buf = wbuf[ks & 1];
#pragma unroll
      for (int t = 0; t < 8; t++) {
        bf16x8 b = *(const bf16x8*)(buf + (t * 16 + c16) * 32 + qs8);
        acc4[t] = MFMA(a, b, acc4[t]);
      }
      if (ks + 1 < 4) stage_write<2, 128>(wbuf[(ks + 1) & 1], sreg, tid);
      __syncthreads();
    }
#pragma unroll
    for (int t = 0; t < 8; t++) {
      const int o = g * 128 + t * 16 + c16;
      const float bias = b2p[o];
#pragma unroll
      for (int r = 0; r < 4; r++) {
        const int grow = m0 + quad * 4 + r;
        float v = acc4[t][r] + bias;
        out[(size_t)grow * 512 + o] = v;
        if (grow < N_ROWS - 1) {
          float d = v - input[(size_t)(grow + 1) * 512 + o];
          p0local += d * d;
        }
      }
    }
  }
#pragma unroll
  for (int off = 32; off > 0; off >>= 1) p0local += __shfl_down(p0local, off);
  if (lane == 0) atomicAdd(p0_accum, p0local);
}

// mu / S / part3 over h. 512 blocks x 128 rows; thread (c=t&63, rg=t>>6)
// covers cols 4c..4c+3, rows start..start+31 (float4 loads, 4-way row ||ism).
__global__ __launch_bounds__(256) void reduce_h(const float* __restrict__ h, float* __restrict__ acc) {
  __shared__ f32x4 cbuf[256];
  __shared__ float redS[256];
  __shared__ float redP[256];
  const int t = threadIdx.x;
  const int c = t & 63;
  const int rg = t >> 6;
  const int start = blockIdx.x * 128 + rg * 32;

  const float* base = h + (size_t)start * 256 + c * 4;
  f32x4 prev = *(const f32x4*)base;
  f32x4 csum = prev;
  f32x4 s2v = prev * prev;
  f32x4 p3v = (f32x4){0.f, 0.f, 0.f, 0.f};
#pragma unroll 8
  for (int r = 1; r < 32; r++) {
    f32x4 v = *(const f32x4*)(base + (size_t)r * 256);
    csum += v;
    s2v += v * v;
    f32x4 d = v - prev;
#pragma unroll
    for (int i = 0; i < 4; i++) p3v[i] += __builtin_fabsf(d[i]);
    prev = v;
  }
  if (start + 32 < N_ROWS) {
    f32x4 v = *(const f32x4*)(base + (size_t)32 * 256);
    f32x4 d = v - prev;
#pragma unroll
    for (int i = 0; i < 4; i++) p3v[i] += __builtin_fabsf(d[i]);
  }
  cbuf[t] = csum;
  redS[t] = s2v[0] + s2v[1] + s2v[2] + s2v[3];
  redP[t] = p3v[0] + p3v[1] + p3v[2] + p3v[3];
  __syncthreads();
  if (rg == 0) {
    f32x4 s = cbuf[c] + cbuf[c + 64] + cbuf[c + 128] + cbuf[c + 192];
    atomicAdd(&acc[4 * c + 0], s[0]);
    atomicAdd(&acc[4 * c + 1], s[1]);
    atomicAdd(&acc[4 * c + 2], s[2]);
    atomicAdd(&acc[4 * c + 3], s[3]);
  }
  for (int s = 128; s > 0; s >>= 1) {
    if (t < s) { redS[t] += redS[t + s]; redP[t] += redP[t + s]; }
    __syncthreads();
  }
  if (t == 0) {
    atomicAdd(&acc[257], redS[0]);
    atomicAdd(&acc[258], redP[0]);
  }
}

__global__ void finalize(const float* __restrict__ acc, float* __restrict__ out) {
  __shared__ float red[256];
  const int t = threadIdx.x;
  red[t] = fabsf(acc[t]);  // |colsum|
  __syncthreads();
  for (int s = 128; s > 0; s >>= 1) {
    if (t < s) red[t] += red[t + s];
    __syncthreads();
  }
  if (t == 0) {
    float part1 = red[0] / 65536.0f / 256.0f;
    float part0 = sqrtf(acc[256]) / 65535.0f;
    float part2 = fabsf(acc[257] / (65536.0f * 256.0f) - 1.0f);
    float part3 = acc[258] / (65535.0f * 256.0f);
    out[(size_t)N_ROWS * 512 + 0] = part0;
    out[(size_t)N_ROWS * 512 + 1] = part1;
    out[(size_t)N_ROWS * 512 + 2] = part2;
    out[(size_t)N_ROWS * 512 + 3] = part3;
  }
}

extern "C" void kernel_launch(void* const* d_in, const int* in_sizes, int n_in,
                              void* d_out, int out_size, void* d_ws, size_t ws_size,
                              hipStream_t stream) {
  const float* input = (const float*)d_in[0];
  const float* h   = (const float*)d_in[1];
  const float* W1  = (const float*)d_in[2];
  const float* b1  = (const float*)d_in[3];
  const float* W12 = (const float*)d_in[4];
  const float* b12 = (const float*)d_in[5];
  const float* W13 = (const float*)d_in[6];
  const float* b13 = (const float*)d_in[7];
  const float* W2  = (const float*)d_in[8];
  const float* b2  = (const float*)d_in[9];
  float* out = (float*)d_out;

  bf16* wp = (bf16*)d_ws;
  float* bp = (float*)((char*)d_ws + BP_OFF_BYTES);
  float* acc = (float*)((char*)d_ws + ACC_OFF_BYTES);

  hipMemsetAsync(acc, 0, ACC_FLOATS * sizeof(float), stream);
  pack_kernel<<<(WP_TOTAL + BP_FLOATS + 255) / 256, 256, 0, stream>>>(
      W1, b1, W12, b12, W13, b13, W2, b2, wp, bp);
  mlp_main<<<N_ROWS / 64, 256, 0, stream>>>(input, h, wp, bp, out, acc + 256);
  reduce_h<<<N_ROWS / 128, 256, 0, stream>>>(h, acc);
  finalize<<<1, 256, 0, stream>>>(acc, out);
}